// Round 6
// baseline (659.891 us; speedup 1.0000x reference)
//
#include <hip/hip_runtime.h>

#define B_SZ 2048
#define T_SZ 2048

using f32x16 = float __attribute__((ext_vector_type(16)));

// DPP move: result[lane] = src[perm(lane)] (quad_perm / row_ror patterns)
template<int CTRL>
__device__ __forceinline__ float dppf(float v) {
  int r = __builtin_amdgcn_update_dpp(0, __builtin_bit_cast(int, v), CTRL, 0xf, 0xf, true);
  return __builtin_bit_cast(float, r);
}

// 1 batch row per wave; four 16-lane groups compute the row REDUNDANTLY.
// Lane owns 4 hidden units: sl, sl+16, sl+32, sl+48 (sl = lane&15).
// Reduce is entirely within 16 lanes: quad xor1/xor2 + row_ror4 + row_ror8
// -> pure DPP, ZERO DS ops on the recurrence chain.
__global__ __launch_bounds__(256) void sss_kernel(
    const float* __restrict__ x0p, const float* __restrict__ up,
    const float* __restrict__ tfp, const float* __restrict__ thp,
    const float* __restrict__ tup, const float* __restrict__ typ,
    const float* __restrict__ W1p, const float* __restrict__ b1p,
    const float* __restrict__ W2p, const float* __restrict__ Whp,
    float* __restrict__ outp)
{
  const int lane = threadIdx.x & 63;
  const int wv   = __builtin_amdgcn_readfirstlane((int)(threadIdx.x >> 6));
  const int b    = blockIdx.x * 4 + wv;   // one wave per batch row
  const int sl   = lane & 15;             // sub-lane within 16-group
  const int k    = lane & 3;              // output channel

  // ---- prologue ----
  // fold K = 2*log2(e) into W1/cc: tanh(a) = 1 - 2/(exp2(K*a)+1)
  const float K = 2.8853900817779268f;
  float w1[4][6], cc[4];
#pragma unroll
  for (int c = 0; c < 4; ++c) {
    const int u = sl + 16 * c;
#pragma unroll
    for (int r = 0; r < 6; ++r) w1[c][r] = W1p[r * 64 + u] * K;
    float t = b1p[u];
#pragma unroll
    for (int q = 0; q < 5; ++q) t = fmaf(tfp[q], W1p[(6 + q) * 64 + u], t);
    cc[c] = t * K;
  }

  const float scale = tup[0] / typ[0];
  // per-lane W2 columns (k, k^1, k^2, k^3) for tree roles (A,B,C,D):
  // v = (A + dppB1(B)) + dpp4E(C + dppB1(D)) yields channel-k quad sums
  // with NO cndmask (xor2 select hoisted into the column choice).
  float wA[4], wB[4], wC[4], wD[4];
#pragma unroll
  for (int c = 0; c < 4; ++c) {
    const int u = sl + 16 * c;
    const float4 w2r = ((const float4*)W2p)[u];
    const float s0 = w2r.x * scale, s1 = w2r.y * scale;
    const float s2 = w2r.z * scale, s3 = w2r.w * scale;
    float col[4] = {s0, s1, s2, s3};
    wA[c] = col[k];
    wB[c] = col[k ^ 1];
    wC[c] = col[k ^ 2];
    wD[c] = col[k ^ 3];
  }

  const float whl = Whp[k];            // Wh[k][0]
  const float th  = thp[0];

  // per-lane clip bounds: components 0..2 -> [0,10], component 3 unbounded
  const float lo = (k == 3) ? -__builtin_inff() : 0.0f;
  const float hi = (k == 3) ?  __builtin_inff() : 10.0f;

  // per-lane state: xlane = x[k] (replicated per quad)
  float xlane = x0p[b * 4 + k];
  float x0v = dppf<0x00>(xlane);
  float x1v = dppf<0x55>(xlane);
  float x2v = dppf<0xAA>(xlane);
  float x3v = dppf<0xFF>(xlane);

  // y0 = h(x_0), UNCLAMPED (matches reference)
  float p0 = xlane * whl;
  p0 += dppf<0xB1>(p0);
  p0 += dppf<0x4E>(p0);
  float yv = p0 + th;

  // ---- per-step direct output store setup (group 0 lanes 0-4 only) ----
  unsigned voff, vinc;
  if (lane < 4) {
    voff = (unsigned)(b * (T_SZ * 4) + lane) * 4u;
    vinc = 16u;
  } else {
    voff = (unsigned)((unsigned)B_SZ * T_SZ * 4u + (unsigned)b * T_SZ) * 4u;
    vinc = (lane == 4) ? 4u : 0u;
  }
  const bool doSt = (lane < 5);
  const bool is4  = (lane == 4);

  const f32x16* up16 = (const f32x16*)(up + (size_t)b * (T_SZ * 2)); // 8 steps/chunk
  char* outB = (char*)outp;

  f32x16 uch = up16[0];
  const int NC = T_SZ / 8;

  for (int c = 0; c < NC; ++c) {
    const int g = (c + 1 < NC) ? c + 1 : NC - 1;   // prefetch next chunk
    const f32x16 unx = up16[g];
#pragma unroll
    for (int jj = 0; jj < 8; ++jj) {
      // ---- emit PRE-update carry (x_step, y_step) ----
      const float vdata = is4 ? yv : xlane;
      if (doSt) *(float*)(outB + voff) = vdata;
      voff += vinc;

      const float u0 = uch[2 * jj];
      const float u1 = uch[2 * jj + 1];

      // u-only part of pre-activation: ready before the reduce lands
      float base[4];
#pragma unroll
      for (int cu = 0; cu < 4; ++cu)
        base[cu] = fmaf(u1, w1[cu][5], fmaf(u0, w1[cu][4], cc[cu]));

      // x part (post-broadcast depth 3) + tanh, 4 units
      float h[4];
#pragma unroll
      for (int cu = 0; cu < 4; ++cu) {
        const float m01 = fmaf(x1v, w1[cu][1], x0v * w1[cu][0]);
        const float m23 = fmaf(x3v, w1[cu][3], x2v * w1[cu][2]);
        const float acc = (base[cu] + m01) + m23;
        const float e  = __builtin_amdgcn_exp2f(acc);
        const float rr = __builtin_amdgcn_rcpf(e + 1.0f);
        h[cu] = fmaf(-2.0f, rr, 1.0f);
      }

      // fold 4 units into quad-tree roles (depth-3 trees)
      const float qA = fmaf(h[1], wA[1], h[0] * wA[0]) + fmaf(h[3], wA[3], h[2] * wA[2]);
      const float qB = fmaf(h[1], wB[1], h[0] * wB[0]) + fmaf(h[3], wB[3], h[2] * wB[2]);
      const float qC = fmaf(h[1], wC[1], h[0] * wC[0]) + fmaf(h[3], wC[3], h[2] * wC[2]);
      const float qD = fmaf(h[1], wD[1], h[0] * wD[0]) + fmaf(h[3], wD[3], h[2] * wD[2]);

      // quad tree (no cndmask) + 16-lane rors: full 64-unit channel sum
      const float r0 = qA + dppf<0xB1>(qB);     // xor1 (quad_perm [1,0,3,2])
      const float r1 = qC + dppf<0xB1>(qD);
      float v = r0 + dppf<0x4E>(r1);            // xor2 (quad_perm [2,3,0,1])
      v += dppf<0x124>(v);                      // row_ror:4
      v += dppf<0x128>(v);                      // row_ror:8 -> 16-lane total

      // per-lane state update: w = pre-clip x_raw[k]
      const float w = xlane + v;
      xlane = __builtin_amdgcn_fmed3f(w, lo, hi);   // clip (comp 3 unbounded)

      // y from PRE-clip state: quad reduce of w*wh
      float p = w * whl;
      p += dppf<0xB1>(p);
      p += dppf<0x4E>(p);
      yv = __builtin_amdgcn_fmed3f(p + th, 0.0f, 10.0f);

      // broadcast clipped state for next step's matvec (within quad)
      x0v = dppf<0x00>(xlane);
      x1v = dppf<0x55>(xlane);
      x2v = dppf<0xAA>(xlane);
      x3v = dppf<0xFF>(xlane);
    }
    uch = unx;
  }
}

extern "C" void kernel_launch(void* const* d_in, const int* in_sizes, int n_in,
                              void* d_out, int out_size, void* d_ws, size_t ws_size,
                              hipStream_t stream) {
  (void)in_sizes; (void)n_in; (void)out_size; (void)d_ws; (void)ws_size;
  sss_kernel<<<dim3(B_SZ / 4), dim3(256), 0, stream>>>(
      (const float*)d_in[0], (const float*)d_in[1], (const float*)d_in[2],
      (const float*)d_in[3], (const float*)d_in[4], (const float*)d_in[5],
      (const float*)d_in[6], (const float*)d_in[7], (const float*)d_in[8],
      (const float*)d_in[9], (float*)d_out);
}

// Round 8
// 359.370 us; speedup vs baseline: 1.8362x; 1.8362x over previous
//
#include <hip/hip_runtime.h>

#define B_SZ 2048
#define T_SZ 2048

using f32x16 = float __attribute__((ext_vector_type(16)));
using f32x2  = float __attribute__((ext_vector_type(2)));

// DPP move: result[lane] = src[perm(lane)] (quad_perm / row_ror patterns)
template<int CTRL>
__device__ __forceinline__ float dppf(float v) {
  int r = __builtin_amdgcn_update_dpp(0, __builtin_bit_cast(int, v), CTRL, 0xf, 0xf, true);
  return __builtin_bit_cast(float, r);
}

__device__ __forceinline__ f32x2 pkfma(f32x2 a, f32x2 b, f32x2 c) {
  return __builtin_elementwise_fma(a, b, c);
}

// 4 batch rows per wave: 16-lane group g = row; lane owns units sl,sl+16,sl+32,sl+48.
// Reduce closes within 16 lanes: quad xor-tree (select-free) + row_ror4 + row_ror8.
// ZERO DS / permlane / readlane on the recurrence chain.
__global__ __launch_bounds__(256) void sss_kernel(
    const float* __restrict__ x0p, const float* __restrict__ up,
    const float* __restrict__ tfp, const float* __restrict__ thp,
    const float* __restrict__ tup, const float* __restrict__ typ,
    const float* __restrict__ W1p, const float* __restrict__ b1p,
    const float* __restrict__ W2p, const float* __restrict__ Whp,
    float* __restrict__ outp)
{
  const int lane = threadIdx.x & 63;
  const int wv   = __builtin_amdgcn_readfirstlane((int)(threadIdx.x >> 6));
  const int grp  = lane >> 4;              // 16-lane group = row within wave
  const int sl   = lane & 15;              // sub-lane within group
  const int k    = lane & 3;               // output channel
  const int b    = blockIdx.x * 16 + wv * 4 + grp;   // batch row

  // ---- prologue ----
  // fold K = 2*log2(e) into W1/cc: tanh(a) = 1 - 2/(exp2(K*a)+1)
  const float K = 2.8853900817779268f;
  // unit pairs packed as f32x2: _01 = units (sl, sl+16), _23 = (sl+32, sl+48)
  f32x2 w1_01[6], w1_23[6];
#pragma unroll
  for (int r = 0; r < 6; ++r) {
    w1_01[r] = f32x2{W1p[r * 64 + sl]      * K, W1p[r * 64 + sl + 16] * K};
    w1_23[r] = f32x2{W1p[r * 64 + sl + 32] * K, W1p[r * 64 + sl + 48] * K};
  }
  float ccs[4];
#pragma unroll
  for (int i = 0; i < 4; ++i) {
    const int u = sl + 16 * i;
    float t = b1p[u];
#pragma unroll
    for (int q = 0; q < 5; ++q) t = fmaf(tfp[q], W1p[(6 + q) * 64 + u], t);
    ccs[i] = t * K;
  }
  const f32x2 cc01 = f32x2{ccs[0], ccs[1]};
  const f32x2 cc23 = f32x2{ccs[2], ccs[3]};

  const float scale = tup[0] / typ[0];
  // role weights (R6-proven select-free column mapping), packed (A,B) / (C,D):
  // v = (qA + dpp_xor1(qB)) + (dpp_xor2(qC) + dpp_xor3(qD)) -> channel-k quad sums
  f32x2 wAB[4], wCD[4];
#pragma unroll
  for (int i = 0; i < 4; ++i) {
    const float4 w2r = ((const float4*)W2p)[sl + 16 * i];
    float col[4] = {w2r.x * scale, w2r.y * scale, w2r.z * scale, w2r.w * scale};
    wAB[i] = f32x2{col[k], col[k ^ 1]};
    wCD[i] = f32x2{col[k ^ 2], col[k ^ 3]};
  }

  const float whl = Whp[k];            // Wh[k][0]
  const float th  = thp[0];

  // per-lane clip bounds: channels 0..2 -> [0,10], channel 3 unbounded
  const float lo = (k == 3) ? -__builtin_inff() : 0.0f;
  const float hi = (k == 3) ?  __builtin_inff() : 10.0f;

  // per-lane state: xlane = x[k] of this lane's row (replicated per quad)
  float xlane = x0p[b * 4 + k];
  float x0v = dppf<0x00>(xlane);
  float x1v = dppf<0x55>(xlane);
  float x2v = dppf<0xAA>(xlane);
  float x3v = dppf<0xFF>(xlane);

  // y0 = h(x_0), UNCLAMPED (matches reference)
  float p0 = xlane * whl;
  p0 += dppf<0xB1>(p0);
  p0 += dppf<0x4E>(p0);
  float yv = p0 + th;

  // ---- per-step direct output store setup ----
  // per group: sub-lanes 0-3 -> outx[b][t][k]; sub-lane 4 -> outy[b][t]
  unsigned voff, vinc;
  if (sl < 4) {
    voff = (unsigned)(b * (T_SZ * 4) + sl) * 4u;
    vinc = 16u;
  } else {
    voff = (unsigned)((unsigned)B_SZ * T_SZ * 4u + (unsigned)b * T_SZ) * 4u;
    vinc = (sl == 4) ? 4u : 0u;
  }
  const bool doSt = (sl < 5);
  const bool is4  = (sl == 4);

  const f32x16* up16 = (const f32x16*)(up + (size_t)b * (T_SZ * 2)); // 8 steps/chunk
  char* outB = (char*)outp;

  f32x16 uch = up16[0];
  const int NC = T_SZ / 8;

  for (int c = 0; c < NC; ++c) {
    const int g = (c + 1 < NC) ? c + 1 : NC - 1;   // prefetch next chunk
    const f32x16 unx = up16[g];
#pragma unroll
    for (int jj = 0; jj < 8; ++jj) {
      // ---- emit PRE-update carry (x_step, y_step), all 4 rows ----
      const float vdata = is4 ? yv : xlane;
      if (doSt) *(float*)(outB + voff) = vdata;
      voff += vinc;

      const float u0 = uch[2 * jj];
      const float u1 = uch[2 * jj + 1];
      const f32x2 u0p = f32x2{u0, u0};
      const f32x2 u1p = f32x2{u1, u1};

      // u-only part (x-independent, schedulable early), packed unit pairs
      const f32x2 b01 = pkfma(u1p, w1_01[5], pkfma(u0p, w1_01[4], cc01));
      const f32x2 b23 = pkfma(u1p, w1_23[5], pkfma(u0p, w1_23[4], cc23));

      // x-part: depth-3 after broadcast, packed
      const f32x2 x0pv = f32x2{x0v, x0v};
      const f32x2 x1pv = f32x2{x1v, x1v};
      const f32x2 x2pv = f32x2{x2v, x2v};
      const f32x2 x3pv = f32x2{x3v, x3v};
      const f32x2 mA01 = pkfma(x1pv, w1_01[1], x0pv * w1_01[0]);
      const f32x2 mB01 = pkfma(x3pv, w1_01[3], x2pv * w1_01[2]);
      const f32x2 a01  = (b01 + mA01) + mB01;
      const f32x2 mA23 = pkfma(x1pv, w1_23[1], x0pv * w1_23[0]);
      const f32x2 mB23 = pkfma(x3pv, w1_23[3], x2pv * w1_23[2]);
      const f32x2 a23  = (b23 + mA23) + mB23;

      // tanh(a) = 1 - 2/(exp2(acc)+1), 4 units (scalar trans ops)
      float h[4];
      {
        const float av[4] = {a01[0], a01[1], a23[0], a23[1]};
#pragma unroll
        for (int i = 0; i < 4; ++i) {
          const float e  = __builtin_amdgcn_exp2f(av[i]);
          const float rr = __builtin_amdgcn_rcpf(e + 1.0f);
          h[i] = fmaf(-2.0f, rr, 1.0f);
        }
      }

      // fold 4 units into tree roles, packed (A,B) and (C,D)
      f32x2 qAB = f32x2{h[0], h[0]} * wAB[0];
      qAB = pkfma(f32x2{h[1], h[1]}, wAB[1], qAB);
      qAB = pkfma(f32x2{h[2], h[2]}, wAB[2], qAB);
      qAB = pkfma(f32x2{h[3], h[3]}, wAB[3], qAB);
      f32x2 qCD = f32x2{h[0], h[0]} * wCD[0];
      qCD = pkfma(f32x2{h[1], h[1]}, wCD[1], qCD);
      qCD = pkfma(f32x2{h[2], h[2]}, wCD[2], qCD);
      qCD = pkfma(f32x2{h[3], h[3]}, wCD[3], qCD);

      // select-free quad tree: xor1 (0xB1), xor2 (0x4E), xor3 = reverse (0x1B)
      float v = (qAB[0] + dppf<0xB1>(qAB[1]))
              + (dppf<0x4E>(qCD[0]) + dppf<0x1B>(qCD[1]));
      v += dppf<0x124>(v);                      // row_ror:4
      v += dppf<0x128>(v);                      // row_ror:8 -> full 64-unit sum

      // per-lane state update: w = pre-clip x_raw[k]
      const float w = xlane + v;
      xlane = __builtin_amdgcn_fmed3f(w, lo, hi);   // clip (channel 3 unbounded)

      // y from PRE-clip state: quad reduce of w*wh
      float p = w * whl;
      p += dppf<0xB1>(p);
      p += dppf<0x4E>(p);
      yv = __builtin_amdgcn_fmed3f(p + th, 0.0f, 10.0f);

      // broadcast clipped state for next step's matvec (within quad)
      x0v = dppf<0x00>(xlane);
      x1v = dppf<0x55>(xlane);
      x2v = dppf<0xAA>(xlane);
      x3v = dppf<0xFF>(xlane);
    }
    uch = unx;
  }
}

extern "C" void kernel_launch(void* const* d_in, const int* in_sizes, int n_in,
                              void* d_out, int out_size, void* d_ws, size_t ws_size,
                              hipStream_t stream) {
  (void)in_sizes; (void)n_in; (void)out_size; (void)d_ws; (void)ws_size;
  sss_kernel<<<dim3(B_SZ / 16), dim3(256), 0, stream>>>(
      (const float*)d_in[0], (const float*)d_in[1], (const float*)d_in[2],
      (const float*)d_in[3], (const float*)d_in[4], (const float*)d_in[5],
      (const float*)d_in[6], (const float*)d_in[7], (const float*)d_in[8],
      (const float*)d_in[9], (float*)d_out);
}